// Round 7
// baseline (1588.620 us; speedup 1.0000x reference)
//
#include <hip/hip_runtime.h>
#include <hip/hip_bf16.h>
#include <cstdint>
#include <cstddef>

// Problem constants
#define E_    8
#define H_    2048
#define I_    2816
#define T_    512
#define NPAIR 1024
#define GRID_ 768          // 3 blocks/CU x 256 CUs: all co-resident (capacity-guaranteed)

// gemm1 tile (round-1 proven core)
#define TM1  192
#define TN1  32
#define MT1  3             // 192 / 4 waves / 16
// gemm2 tile
#define TM2  64
#define TN2  16
#define BK   64
#define LDSB 72            // padded LDS row stride (bf16): 144 B (16B-aligned rows)

typedef __attribute__((ext_vector_type(8))) short          bf16x8;
typedef __attribute__((ext_vector_type(4))) float          f32x4;
typedef __attribute__((ext_vector_type(8))) unsigned short u16x8;

__device__ __forceinline__ unsigned short f2bf(float f){
  union { float f; unsigned u; } a; a.f = f;
  unsigned u = a.u;
  unsigned r = u + 0x7fffu + ((u >> 16) & 1u);   // RNE
  return (unsigned short)(r >> 16);
}

__device__ __forceinline__ void cvt4(u16x8& dst, int base, const float4 v, float s){
  __hip_bfloat162 p0 = __float22bfloat162_rn(float2{v.x*s, v.y*s});
  __hip_bfloat162 p1 = __float22bfloat162_rn(float2{v.z*s, v.w*s});
  union { __hip_bfloat162 b; unsigned u; } a0{p0}, a1{p1};
  dst[base+0] = (unsigned short)(a0.u & 0xffff);
  dst[base+1] = (unsigned short)(a0.u >> 16);
  dst[base+2] = (unsigned short)(a1.u & 0xffff);
  dst[base+3] = (unsigned short)(a1.u >> 16);
}

// LDS-only barrier: drain LDS ops, keep global prefetch loads in flight.
__device__ __forceinline__ void sync_lds(){
  asm volatile("s_waitcnt lgkmcnt(0)\n\ts_barrier" ::: "memory");
}

// Grid barrier: one monotone counter per phase (zeroed by route_kernel).
// Release: __threadfence (agent-scope L2 writeback) before the arrive-add.
// Acquire: polling acquire-load + trailing __threadfence per thread
// (invalidates stale lines). Safe because all GRID_ blocks are co-resident.
__device__ __forceinline__ void gridbar(int* bar){
  __syncthreads();
  if (threadIdx.x == 0){
    __threadfence();
    __hip_atomic_fetch_add(bar, 1, __ATOMIC_ACQ_REL, __HIP_MEMORY_SCOPE_AGENT);
    while (__hip_atomic_load(bar, __ATOMIC_ACQUIRE, __HIP_MEMORY_SCOPE_AGENT) < GRID_)
      __builtin_amdgcn_s_sleep(2);
  }
  __syncthreads();
  __threadfence();
}

// ---------------------------------------------------------------------------
// Routing: bucket 1024 (t,k) pairs by expert; inverse map; zero grid barriers.
// ---------------------------------------------------------------------------
__global__ void route_kernel(const int* __restrict__ ids,
                             int* __restrict__ offs, int* __restrict__ ptok,
                             int* __restrict__ sop, int* __restrict__ bar){
  __shared__ int scnt[E_];
  __shared__ int scur[E_];
  const int tid = threadIdx.x;
  if (tid < E_) scnt[tid] = 0;
  if (tid < 4)  bar[tid] = 0;
  __syncthreads();
  const int e = ids[tid];
  atomicAdd(&scnt[e], 1);
  __syncthreads();
  if (tid == 0){
    int s = 0;
    for (int i = 0; i < E_; i++){ offs[i] = s; scur[i] = s; s += scnt[i]; }
    offs[E_] = s;
  }
  __syncthreads();
  const int pos = atomicAdd(&scur[e], 1);
  ptok[pos] = tid >> 1;
  sop[tid]  = pos;
}

// ---------------------------------------------------------------------------
// Fused persistent MoE kernel: prep | BAR | gemm1 | BAR | gemm2 | BAR | combine
// 768 blocks x 256 threads, all co-resident. Expert = blockIdx.x & 7 keeps
// per-expert weight/act streams XCD-affine (round-robin wg->XCD).
// gemm1: 88 jobs/XCD over 96 blocks -> exactly <=1 job/block (zero tail).
// gemm2: 256 jobs/XCD over 96 blocks (TN2=16, M split in 2) -> <=3 jobs.
// Inner K-loops: round-1 cores verbatim (reg-staged B + dequant to bf16 LDS,
// distance-2 reg prefetch, double LDS buffer, LDS-only barriers).
// ---------------------------------------------------------------------------
__global__ __launch_bounds__(256, 3)
void moe_kernel(const float* __restrict__ x,
                const float* __restrict__ w13, const float* __restrict__ s13,
                const float* __restrict__ w2,  const float* __restrict__ s2,
                const float* __restrict__ tw,
                const int* __restrict__ offs, const int* __restrict__ ptok,
                const int* __restrict__ sop,  int* __restrict__ bar,
                unsigned short* __restrict__ xg, unsigned short* __restrict__ act,
                float* __restrict__ buf, float* __restrict__ out)
{
  const int b    = blockIdx.x;
  const int tid  = threadIdx.x;
  const int wv   = tid >> 6;
  const int lane = tid & 63;
  const int quad = lane >> 4;
  const int l16  = lane & 15;

  __shared__ __align__(16) unsigned short Bs[2][2*TN1][LDSB];   // 18432 B

  // ---------------- phase 0: prep (token-ordered xg, bf16) ----------------
  if (b < T_){
    const int k0 = tid * 8;
    const float4 v0 = *(const float4*)(x + (size_t)b*H_ + k0);
    const float4 v1 = *(const float4*)(x + (size_t)b*H_ + k0 + 4);
    u16x8 o;
    cvt4(o, 0, v0, 1.f);
    cvt4(o, 4, v1, 1.f);
    *(u16x8*)(xg + (size_t)b*H_ + k0) = o;
  }
  gridbar(bar + 0);

  // ---------------- phase 1: gemm1  act = silu(x@Wg^T)*(x@Wu^T) -----------
  {
    const int e = b & 7;
    const int q = b >> 3;             // 0..95 within XCD-affine group
    if (q < I_/TN1){                  // 88 jobs per expert
      const int nb  = q * TN1;
      const int off = offs[e];
      const int cnt = offs[e+1] - off;

      const float* w13e = w13 + (size_t)e * (2*I_) * H_;
      const float* s13e = s13 + (size_t)e * 44 * 16;   // (2I/128)x(H/128)

      // B staging: row br (0..63: gate 0..31, up 32..63), 4 thr/row, 16 f32
      const int br = tid >> 2;
      const int bc = tid & 3;
      const int grow = (br < TN1) ? (nb + br) : (I_ + nb + (br - TN1));
      const float* bp = w13e + (size_t)grow * H_ + bc*16;
      const int srow  = (((br < TN1) ? 0 : 22) + (nb >> 7)) * 16;

      for (int m0 = 0; m0 < cnt; m0 += TM1){
        const int rows = min(TM1, cnt - m0);

        // A row pointers via ptok indirection (token-ordered xg)
        const unsigned short* aP[MT1];
        #pragma unroll
        for (int mt = 0; mt < MT1; mt++){
          int sl = off + m0 + wv*(TM1/4) + mt*16 + l16;
          sl = min(sl, NPAIR - 1);
          aP[mt] = xg + (size_t)ptok[sl] * H_ + quad*8;
        }

        f32x4 acc[2][MT1][2];
        #pragma unroll
        for (int h = 0; h < 2; h++)
          #pragma unroll
          for (int mt = 0; mt < MT1; mt++)
            #pragma unroll
            for (int nt = 0; nt < 2; nt++)
              acc[h][mt][nt] = (f32x4){0.f, 0.f, 0.f, 0.f};

        float4 R0[4], R1[4];
        bf16x8 A0[2][MT1], A1[2][MT1];
        float  sE, sO;

        auto loadB = [&](int t, float4* R){
          const float* p = bp + t*BK;
          #pragma unroll
          for (int j = 0; j < 4; j++) R[j] = *(const float4*)(p + j*4);
        };
        auto loadA = [&](int t, bf16x8 (*A)[MT1]){
          #pragma unroll
          for (int kk = 0; kk < 2; kk++)
            #pragma unroll
            for (int mt = 0; mt < MT1; mt++)
              A[kk][mt] = *(const bf16x8*)(aP[mt] + t*BK + kk*32);
        };
        auto storeB = [&](const float4* R, float s, int bi){
          u16x8 w0, w1;
          cvt4(w0, 0, R[0], s); cvt4(w0, 4, R[1], s);
          cvt4(w1, 0, R[2], s); cvt4(w1, 4, R[3], s);
          *(u16x8*)&Bs[bi][br][bc*16]     = w0;
          *(u16x8*)&Bs[bi][br][bc*16 + 8] = w1;
        };
        auto mfma = [&](int bi, bf16x8 (*A)[MT1]){
          #pragma unroll
          for (int kk = 0; kk < 2; kk++)
            #pragma unroll
            for (int hh = 0; hh < 2; hh++)
              #pragma unroll
              for (int nt = 0; nt < 2; nt++){
                bf16x8 bv = *(const bf16x8*)&Bs[bi][hh*TN1 + nt*16 + l16][kk*32 + quad*8];
                #pragma unroll
                for (int mt = 0; mt < MT1; mt++)
                  acc[hh][mt][nt] = __builtin_amdgcn_mfma_f32_16x16x32_bf16(A[kk][mt], bv, acc[hh][mt][nt], 0, 0, 0);
              }
        };

        const int NITER = H_/BK;   // 32
        loadB(0, R0); sE = s13e[srow];
        loadB(1, R1); sO = s13e[srow];
        loadA(0, A0);
        storeB(R0, sE, 0);
        sync_lds();
        for (int i = 0; i < NITER; i += 2){
          if (i+2 < NITER){ loadB(i+2, R0); sE = s13e[srow + ((i+2) >> 1)]; }
          loadA(i+1, A1);
          mfma(0, A0);
          storeB(R1, sO, 1);
          sync_lds();
          if (i+3 < NITER){ loadB(i+3, R1); sO = s13e[srow + ((i+3) >> 1)]; }
          if (i+2 < NITER) loadA(i+2, A0);
          mfma(1, A1);
          if (i+2 < NITER){ storeB(R0, sE, 0); sync_lds(); }
        }

        // epilogue: act = silu(gate)*up
        #pragma unroll
        for (int mt = 0; mt < MT1; mt++){
          #pragma unroll
          for (int nt = 0; nt < 2; nt++){
            #pragma unroll
            for (int r = 0; r < 4; r++){
              const int m = wv*(TM1/4) + mt*16 + quad*4 + r;
              if (m < rows){
                const float g = acc[0][mt][nt][r];
                const float u = acc[1][mt][nt][r];
                const float sg = g / (1.f + __expf(-g));
                act[(size_t)(off + m0 + m)*I_ + (nb + nt*16 + l16)] = f2bf(sg * u);
              }
            }
          }
        }
      }
    }
  }
  gridbar(bar + 1);

  // ---------------- phase 2: gemm2  buf = act @ W2^T ----------------------
  {
    const int e   = b & 7;
    const int off = offs[e];
    const int cnt = offs[e+1] - off;
    const float* w2e = w2 + (size_t)e * H_ * I_;
    const float* s2e = s2 + (size_t)e * 16 * 22;       // (H/128)x(I/128)
    auto Bs2 = reinterpret_cast<unsigned short (*)[TN2][LDSB]>(&Bs[0][0][0]);

    const int br2 = tid >> 4;          // 0..15
    const int bc2 = tid & 15;          // x4 floats

    for (int r = (b >> 3); r < 256; r += 96){      // 256 jobs/expert
      const int nb = (r & 127) * TN2;
      const int mh = r >> 7;                       // m-half 0/1
      const float* bp = w2e + (size_t)(nb + br2) * I_ + bc2*4;
      const int srow  = (nb >> 7) * 22;

      for (int m0 = mh*TM2; m0 < cnt; m0 += 2*TM2){
        const int rows = min(TM2, cnt - m0);

        int sl = off + m0 + wv*16 + l16;
        sl = min(sl, NPAIR - 1);
        const unsigned short* aP = act + (size_t)sl * I_ + quad*8;

        f32x4 acc2 = (f32x4){0.f, 0.f, 0.f, 0.f};

        float4 R0, R1;
        bf16x8 A0[2], A1[2];
        float  sE, sO;

        auto loadB = [&](int t, float4& R){ R = *(const float4*)(bp + t*BK); };
        auto loadA = [&](int t, bf16x8* A){
          #pragma unroll
          for (int kk = 0; kk < 2; kk++)
            A[kk] = *(const bf16x8*)(aP + t*BK + kk*32);
        };
        auto storeB = [&](float4 R, float s, int bi){
          u16x8 w; cvt4(w, 0, R, s);
          uint2 v;
          v.x = (unsigned)w[0] | ((unsigned)w[1] << 16);
          v.y = (unsigned)w[2] | ((unsigned)w[3] << 16);
          *(uint2*)&Bs2[bi][br2][bc2*4] = v;
        };
        auto mfma = [&](int bi, bf16x8* A){
          #pragma unroll
          for (int kk = 0; kk < 2; kk++){
            bf16x8 bv = *(const bf16x8*)&Bs2[bi][l16][kk*32 + quad*8];
            acc2 = __builtin_amdgcn_mfma_f32_16x16x32_bf16(A[kk], bv, acc2, 0, 0, 0);
          }
        };

        const int NITER = I_/BK;   // 44
        loadB(0, R0); sE = s2e[srow];
        loadB(1, R1); sO = s2e[srow];
        loadA(0, A0);
        storeB(R0, sE, 0);
        sync_lds();
        for (int i = 0; i < NITER; i += 2){
          if (i+2 < NITER){ loadB(i+2, R0); sE = s2e[srow + ((i+2) >> 1)]; }
          loadA(i+1, A1);
          mfma(0, A0);
          storeB(R1, sO, 1);
          sync_lds();
          if (i+3 < NITER){ loadB(i+3, R1); sO = s2e[srow + ((i+3) >> 1)]; }
          if (i+2 < NITER) loadA(i+2, A0);
          mfma(1, A1);
          if (i+2 < NITER){ storeB(R0, sE, 0); sync_lds(); }
        }

        #pragma unroll
        for (int rr = 0; rr < 4; rr++){
          const int m = wv*16 + quad*4 + rr;
          if (m < rows)
            buf[(size_t)(off + m0 + m)*H_ + (nb + l16)] = acc2[rr];
        }
      }
    }
  }
  gridbar(bar + 2);

  // ---------------- phase 3: combine --------------------------------------
  for (int i = b*256 + tid; i < T_*(H_/4); i += GRID_*256){
    const int t = i >> 9;
    const int c = i & 511;
    const int s0 = sop[2*t], s1 = sop[2*t+1];
    const float w0 = tw[2*t], w1 = tw[2*t+1];
    const float4 v0 = ((const float4*)buf)[(size_t)s0*(H_/4) + c];
    const float4 v1 = ((const float4*)buf)[(size_t)s1*(H_/4) + c];
    float4 o;
    o.x = w0*v0.x + w1*v1.x;
    o.y = w0*v0.y + w1*v1.y;
    o.z = w0*v0.z + w1*v1.z;
    o.w = w0*v0.w + w1*v1.w;
    ((float4*)out)[i] = o;
  }
}

// ---------------------------------------------------------------------------
extern "C" void kernel_launch(void* const* d_in, const int* in_sizes, int n_in,
                              void* d_out, int out_size, void* d_ws, size_t ws_size,
                              hipStream_t stream){
  const float* x   = (const float*)d_in[0];
  const int*   ids = (const int*)  d_in[1];
  const float* tw  = (const float*)d_in[2];
  const float* w13 = (const float*)d_in[3];
  const float* s13 = (const float*)d_in[4];
  const float* w2  = (const float*)d_in[5];
  const float* s2  = (const float*)d_in[6];
  float* out = (float*)d_out;

  char* ws = (char*)d_ws;
  int* offs = (int*)ws;                                   // 9 ints @ 0
  int* bar  = (int*)(ws + 128);                           // 4 ints (grid barriers)
  int* ptok = (int*)(ws + 256);                           // 1024 ints
  int* sop  = (int*)(ws + 256 + 4096);                    // 1024 ints
  unsigned short* xg  = (unsigned short*)(ws + 16384);                 // [512][H] bf16
  unsigned short* act = (unsigned short*)(ws + 16384 + 2097152);       // [1024][I] bf16
  float*          buf = (float*)(ws + 16384 + 2097152 + 5767168);      // [1024][H] f32

  route_kernel<<<1, NPAIR, 0, stream>>>(ids, offs, ptok, sop, bar);
  moe_kernel  <<<GRID_, 256, 0, stream>>>(x, w13, s13, w2, s2, tw,
                                          offs, ptok, sop, bar,
                                          xg, act, buf, out);
}